// Round 1
// baseline (2050.440 us; speedup 1.0000x reference)
//
#include <hip/hip_runtime.h>
#include <hip/hip_bf16.h>

// Problem constants (fixed by setup_inputs)
constexpr int T_ = 4, B_ = 8, N_ = 1024, C_ = 512, H_ = 8, D_ = 64;
constexpr int M_ = B_ * N_;   // 8192 rows per timestep

#define TAU_INV 0.5f
#define V_TH    1.0f
#define BN_EPS  1e-5f

__device__ inline float toF(float v) { return v; }
__device__ inline float toF(__hip_bfloat16 v) { return __bfloat162float(v); }
__device__ inline void stF(float* p, float v) { *p = v; }
__device__ inline void stF(__hip_bfloat16* p, float v) { *p = __float2bfloat16(v); }

// ---------------------------------------------------------------------------
// Fused GEMM (+bias) + BatchNorm(eval) + multi-step LIF.
//   X: (T, M, K)  input (fp32 activations, or bf16 binary spikes)
//   W: (Cout, K)  torch convention: y[.,d] = sum_c x[c] * W[d,c]
//   bn: 4 rows of Cout: gamma, beta, mean, var
//   S: (T, M, Cout) spike output ({0,1}, bf16 or fp32)
// Each block owns a 64x64 output tile and iterates t=0..T-1 keeping the LIF
// membrane in registers (LIF couples timesteps).
// ---------------------------------------------------------------------------
template <typename TIn, typename TOut>
__global__ __launch_bounds__(256) void gemm_bn_lif(
    const TIn* __restrict__ X, const float* __restrict__ W,
    const float* __restrict__ bias, const float* __restrict__ bn,
    TOut* __restrict__ S, int M, int K, int Cout, int T)
{
  __shared__ float As[64][65];
  __shared__ float Bs[64][65];
  const int tx = threadIdx.x, ty = threadIdx.y;       // 16 x 16
  const int lid = ty * 16 + tx;
  const int bm = blockIdx.y * 64;
  const int bn0 = blockIdx.x * 64;

  // Per-thread output columns: bn0 + tx*4 + j
  float g[4], be[4], mu[4], inv[4], bi[4];
#pragma unroll
  for (int j = 0; j < 4; ++j) {
    int d = bn0 + tx * 4 + j;
    g[j]   = bn[d];
    be[j]  = bn[Cout + d];
    mu[j]  = bn[2 * Cout + d];
    inv[j] = 1.0f / sqrtf(bn[3 * Cout + d] + BN_EPS);
    bi[j]  = bias[d];
  }

  float mem[4][4];
#pragma unroll
  for (int i = 0; i < 4; ++i)
#pragma unroll
    for (int j = 0; j < 4; ++j) mem[i][j] = 0.0f;

  for (int t = 0; t < T; ++t) {
    const TIn* A = X + (size_t)t * M * K;
    float acc[4][4];
#pragma unroll
    for (int i = 0; i < 4; ++i)
#pragma unroll
      for (int j = 0; j < 4; ++j) acc[i][j] = 0.0f;

    for (int k0 = 0; k0 < K; k0 += 64) {
#pragma unroll
      for (int i = 0; i < 16; ++i) {
        int idx = lid + i * 256;
        int r = idx >> 6, c = idx & 63;
        As[r][c] = toF(A[(size_t)(bm + r) * K + k0 + c]);
      }
#pragma unroll
      for (int i = 0; i < 16; ++i) {
        int idx = lid + i * 256;
        int d = idx >> 6, c = idx & 63;
        Bs[c][d] = W[(size_t)(bn0 + d) * K + k0 + c];   // transpose into LDS
      }
      __syncthreads();
#pragma unroll
      for (int kk = 0; kk < 64; ++kk) {
        float a[4], b[4];
#pragma unroll
        for (int i = 0; i < 4; ++i) a[i] = As[ty * 4 + i][kk];
#pragma unroll
        for (int j = 0; j < 4; ++j) b[j] = Bs[kk][tx * 4 + j];
#pragma unroll
        for (int i = 0; i < 4; ++i)
#pragma unroll
          for (int j = 0; j < 4; ++j) acc[i][j] += a[i] * b[j];
      }
      __syncthreads();
    }

    // Epilogue: bias -> BN(eval) -> LIF step t
#pragma unroll
    for (int i = 0; i < 4; ++i) {
      int row = bm + ty * 4 + i;
#pragma unroll
      for (int j = 0; j < 4; ++j) {
        float y = acc[i][j] + bi[j];
        y = (y - mu[j]) * inv[j] * g[j] + be[j];
        float m2 = mem[i][j] + (y - mem[i][j]) * TAU_INV;
        float s = (m2 - V_TH >= 0.0f) ? 1.0f : 0.0f;
        stF(&S[((size_t)t * M + row) * Cout + bn0 + tx * 4 + j], s);
        mem[i][j] = (s != 0.0f) ? 0.0f : m2;
      }
    }
  }
}

// ---------------------------------------------------------------------------
// Linear attention per (t,b,h): kv = k^T v / N (64x64), y = q @ kv (1024x64).
// Spikes are {0,1} so all arithmetic here is exact in fp32.
// ---------------------------------------------------------------------------
__global__ __launch_bounds__(256) void attn_kernel(
    const __hip_bfloat16* __restrict__ Q,
    const __hip_bfloat16* __restrict__ Kk,
    const __hip_bfloat16* __restrict__ V,
    float* __restrict__ Y)
{
  __shared__ float s1[64][65];
  __shared__ float s2[64][65];
  __shared__ float kv[64][65];
  const int tid = threadIdx.x;
  const int h = blockIdx.x, b = blockIdx.y, t = blockIdx.z;
  const size_t base = ((size_t)t * B_ + b) * (size_t)N_ * C_ + (size_t)h * D_;
  const int d0 = (tid >> 4) * 4;
  const int e0 = (tid & 15) * 4;

  // Phase 1: kv[d][e] = sum_n k[n,d] * v[n,e]
  float acc[4][4];
#pragma unroll
  for (int i = 0; i < 4; ++i)
#pragma unroll
    for (int j = 0; j < 4; ++j) acc[i][j] = 0.0f;

  for (int nc = 0; nc < N_; nc += 64) {
#pragma unroll
    for (int i = 0; i < 16; ++i) {
      int idx = tid + i * 256;
      int r = idx >> 6, c = idx & 63;
      s1[r][c] = __bfloat162float(Kk[base + (size_t)(nc + r) * C_ + c]);
      s2[r][c] = __bfloat162float(V[base + (size_t)(nc + r) * C_ + c]);
    }
    __syncthreads();
#pragma unroll
    for (int nn = 0; nn < 64; ++nn) {
      float a[4], bb[4];
#pragma unroll
      for (int i = 0; i < 4; ++i) a[i] = s1[nn][d0 + i];
#pragma unroll
      for (int j = 0; j < 4; ++j) bb[j] = s2[nn][e0 + j];
#pragma unroll
      for (int i = 0; i < 4; ++i)
#pragma unroll
        for (int j = 0; j < 4; ++j) acc[i][j] += a[i] * bb[j];
    }
    __syncthreads();
  }
#pragma unroll
  for (int i = 0; i < 4; ++i)
#pragma unroll
    for (int j = 0; j < 4; ++j)
      kv[d0 + i][e0 + j] = acc[i][j] * (1.0f / (float)N_);
  __syncthreads();

  // Phase 2: y[n,e] = sum_d q[n,d] * kv[d,e]
  for (int rc = 0; rc < N_; rc += 64) {
#pragma unroll
    for (int i = 0; i < 16; ++i) {
      int idx = tid + i * 256;
      int r = idx >> 6, c = idx & 63;
      s1[r][c] = __bfloat162float(Q[base + (size_t)(rc + r) * C_ + c]);
    }
    __syncthreads();
    float o[4][4];
#pragma unroll
    for (int i = 0; i < 4; ++i)
#pragma unroll
      for (int j = 0; j < 4; ++j) o[i][j] = 0.0f;
#pragma unroll
    for (int d = 0; d < 64; ++d) {
      float a[4], bb[4];
#pragma unroll
      for (int i = 0; i < 4; ++i) a[i] = s1[d0 + i][d];
#pragma unroll
      for (int j = 0; j < 4; ++j) bb[j] = kv[d][e0 + j];
#pragma unroll
      for (int i = 0; i < 4; ++i)
#pragma unroll
        for (int j = 0; j < 4; ++j) o[i][j] += a[i] * bb[j];
    }
#pragma unroll
    for (int i = 0; i < 4; ++i)
#pragma unroll
      for (int j = 0; j < 4; ++j)
        Y[base + (size_t)(rc + d0 + i) * C_ + e0 + j] = o[i][j];
    __syncthreads();
  }
}

// ---------------------------------------------------------------------------
// Elementwise multi-step LIF (attn_lif): reads Y (T,M,C) fp32, writes bf16 spikes.
// ---------------------------------------------------------------------------
__global__ __launch_bounds__(256) void lif_ew(
    const float* __restrict__ Y, __hip_bfloat16* __restrict__ S,
    size_t npt, int T)
{
  size_t idx = (size_t)blockIdx.x * blockDim.x + threadIdx.x;
  if (idx >= npt) return;
  float mem = 0.0f;
  for (int t = 0; t < T; ++t) {
    float y = Y[(size_t)t * npt + idx];
    mem = mem + (y - mem) * TAU_INV;
    float s = (mem - V_TH >= 0.0f) ? 1.0f : 0.0f;
    S[(size_t)t * npt + idx] = __float2bfloat16(s);
    mem = (s != 0.0f) ? 0.0f : mem;
  }
}

extern "C" void kernel_launch(void* const* d_in, const int* in_sizes, int n_in,
                              void* d_out, int out_size, void* d_ws, size_t ws_size,
                              hipStream_t stream)
{
  const float* x   = (const float*)d_in[0];
  const float* Wq  = (const float*)d_in[1];
  const float* bq  = (const float*)d_in[2];
  const float* Wk  = (const float*)d_in[3];
  const float* bk  = (const float*)d_in[4];
  const float* Wv  = (const float*)d_in[5];
  const float* bv  = (const float*)d_in[6];
  const float* Wp  = (const float*)d_in[7];
  const float* bp  = (const float*)d_in[8];
  const float* bnp = (const float*)d_in[9];   // (4 layers, 4, C)
  float* out = (float*)d_out;

  char* ws = (char*)d_ws;
  const size_t nElem = (size_t)T_ * M_ * C_;   // 16,777,216
  __hip_bfloat16* q_s = (__hip_bfloat16*)ws; ws += nElem * sizeof(__hip_bfloat16);
  __hip_bfloat16* k_s = (__hip_bfloat16*)ws; ws += nElem * sizeof(__hip_bfloat16);
  __hip_bfloat16* v_s = (__hip_bfloat16*)ws; ws += nElem * sizeof(__hip_bfloat16);
  __hip_bfloat16* a_s = (__hip_bfloat16*)ws; ws += nElem * sizeof(__hip_bfloat16);
  float*          Y   = (float*)ws;          ws += nElem * sizeof(float);

  dim3 gg(C_ / 64, M_ / 64);   // (8, 128)
  dim3 bb(16, 16);

  gemm_bn_lif<float, __hip_bfloat16><<<gg, bb, 0, stream>>>(
      x, Wq, bq, bnp + 0 * 4 * C_, q_s, M_, C_, C_, T_);
  gemm_bn_lif<float, __hip_bfloat16><<<gg, bb, 0, stream>>>(
      x, Wk, bk, bnp + 1 * 4 * C_, k_s, M_, C_, C_, T_);
  gemm_bn_lif<float, __hip_bfloat16><<<gg, bb, 0, stream>>>(
      x, Wv, bv, bnp + 2 * 4 * C_, v_s, M_, C_, C_, T_);

  attn_kernel<<<dim3(H_, B_, T_), 256, 0, stream>>>(q_s, k_s, v_s, Y);

  const size_t npt = (size_t)M_ * C_;          // 4,194,304 per timestep
  lif_ew<<<dim3((unsigned)((npt + 255) / 256)), 256, 0, stream>>>(Y, a_s, npt, T_);

  gemm_bn_lif<__hip_bfloat16, float><<<gg, bb, 0, stream>>>(
      a_s, Wp, bp, bnp + 3 * 4 * C_, out, M_, C_, C_, T_);
}

// Round 2
// 1201.955 us; speedup vs baseline: 1.7059x; 1.7059x over previous
//
#include <hip/hip_runtime.h>
#include <hip/hip_bf16.h>

// Problem constants (fixed by setup_inputs)
constexpr int T_ = 4, B_ = 8, N_ = 1024, C_ = 512, H_ = 8, D_ = 64;
constexpr int M_ = B_ * N_;   // 8192 rows per timestep
constexpr int K_ = 512;

#define TAU_INV 0.5f
#define V_TH    1.0f
#define BN_EPS  1e-5f

// ---- load 4 consecutive elements as float ---------------------------------
__device__ __forceinline__ void ld4(const float* p, float* d) {
  const float4 v = *(const float4*)p;
  d[0] = v.x; d[1] = v.y; d[2] = v.z; d[3] = v.w;
}
__device__ __forceinline__ void ld4(const __hip_bfloat16* p, float* d) {
  const ushort4 u = *(const ushort4*)p;
  d[0] = __bfloat162float(*(const __hip_bfloat16*)&u.x);
  d[1] = __bfloat162float(*(const __hip_bfloat16*)&u.y);
  d[2] = __bfloat162float(*(const __hip_bfloat16*)&u.z);
  d[3] = __bfloat162float(*(const __hip_bfloat16*)&u.w);
}
// ---- store 4 consecutive spike values -------------------------------------
__device__ __forceinline__ void st4(__hip_bfloat16* p, const float* s) {
  ushort4 u;
  *(__hip_bfloat16*)&u.x = __float2bfloat16(s[0]);
  *(__hip_bfloat16*)&u.y = __float2bfloat16(s[1]);
  *(__hip_bfloat16*)&u.z = __float2bfloat16(s[2]);
  *(__hip_bfloat16*)&u.w = __float2bfloat16(s[3]);
  *(ushort4*)p = u;
}
__device__ __forceinline__ void st4(float* p, const float* s) {
  *(float4*)p = make_float4(s[0], s[1], s[2], s[3]);
}

// ---------------------------------------------------------------------------
// Fused GEMM (+bias) + BN(eval) + multi-step LIF, vector-fp32.
// BIT-EXACTNESS CONTRACT: each output's k-summation is a single fp32
// accumulator over k = 0..511 STRICTLY ASCENDING (fmac chain), and the
// epilogue expressions are textually identical to the round-1 kernel that
// matched the reference with absmax 0.0. Do not reorder / split k.
//
// Block tile TM x TN, 256 threads (16x16), thread tile (TM/16)x(TN/16)
// arranged as GM x GN groups of float4 strided 64 apart (bank-conflict-free
// ds_read_b128 in the hot loop).
// ---------------------------------------------------------------------------
template <int TM, int TN, typename TIn, typename TOut>
__device__ __forceinline__ void gemm_bn_lif_body(
    const TIn* __restrict__ X, const float* __restrict__ W,
    const float* __restrict__ bias, const float* __restrict__ bnp,
    TOut* __restrict__ S, int bm, int bn0)
{
  constexpr int BK = 32;
  constexpr int GM = TM / 64;           // float4 row groups per thread
  constexpr int GN = TN / 64;           // float4 col groups per thread
  __shared__ __align__(16) float As[BK][TM + 4];   // k-major, pad keeps 16B align
  __shared__ __align__(16) float Bs[BK][TN + 4];

  const int tx = threadIdx.x, ty = threadIdx.y;   // 16 x 16
  const int lid = ty * 16 + tx;
  const int kq = (lid & 7) * 4;                   // k offset within chunk
  const int r0 = lid >> 3;                        // 0..31

  // BN constants per output column (loaded once; bn layout: g, be, mu, var)
  float gg[GN][4], be[GN][4], mu[GN][4], inv[GN][4], bi[GN][4];
#pragma unroll
  for (int h = 0; h < GN; ++h)
#pragma unroll
    for (int j = 0; j < 4; ++j) {
      const int d = bn0 + h * 64 + tx * 4 + j;
      gg[h][j]  = bnp[d];
      be[h][j]  = bnp[C_ + d];
      mu[h][j]  = bnp[2 * C_ + d];
      inv[h][j] = 1.0f / sqrtf(bnp[3 * C_ + d] + BN_EPS);
      bi[h][j]  = bias[d];
    }

  float mem[GM][GN][4][4];
#pragma unroll
  for (int g = 0; g < GM; ++g)
#pragma unroll
    for (int h = 0; h < GN; ++h)
#pragma unroll
      for (int i = 0; i < 4; ++i)
#pragma unroll
        for (int j = 0; j < 4; ++j) mem[g][h][i][j] = 0.0f;

  for (int t = 0; t < T_; ++t) {
    const TIn* A = X + (size_t)t * M_ * K_;
    float acc[GM][GN][4][4];
#pragma unroll
    for (int g = 0; g < GM; ++g)
#pragma unroll
      for (int h = 0; h < GN; ++h)
#pragma unroll
        for (int i = 0; i < 4; ++i)
#pragma unroll
          for (int j = 0; j < 4; ++j) acc[g][h][i][j] = 0.0f;

    for (int k0 = 0; k0 < K_; k0 += BK) {
      // ---- stage A (TM x BK), transposed to k-major --------------------
#pragma unroll
      for (int mi = 0; mi < TM / 32; ++mi) {
        const int m = r0 + 32 * mi;
        float tmp[4];
        ld4(&A[(size_t)(bm + m) * K_ + k0 + kq], tmp);
#pragma unroll
        for (int j = 0; j < 4; ++j) As[kq + j][m] = tmp[j];
      }
      // ---- stage B (TN x BK from W row-major), transposed --------------
#pragma unroll
      for (int ni = 0; ni < TN / 32; ++ni) {
        const int n = r0 + 32 * ni;
        float tmp[4];
        ld4(&W[(size_t)(bn0 + n) * K_ + k0 + kq], tmp);
#pragma unroll
        for (int j = 0; j < 4; ++j) Bs[kq + j][n] = tmp[j];
      }
      __syncthreads();

      // ---- hot loop: k strictly ascending ------------------------------
#pragma unroll
      for (int kk = 0; kk < BK; ++kk) {
        float a[GM][4], b[GN][4];
#pragma unroll
        for (int g = 0; g < GM; ++g)
          ld4(&As[kk][g * 64 + ty * 4], a[g]);
#pragma unroll
        for (int h = 0; h < GN; ++h)
          ld4(&Bs[kk][h * 64 + tx * 4], b[h]);
#pragma unroll
        for (int g = 0; g < GM; ++g)
#pragma unroll
          for (int h = 0; h < GN; ++h)
#pragma unroll
            for (int i = 0; i < 4; ++i)
#pragma unroll
              for (int j = 0; j < 4; ++j)
                acc[g][h][i][j] += a[g][i] * b[h][j];
      }
      __syncthreads();
    }

    // ---- epilogue: bias -> BN -> LIF step t (identical expressions) ----
#pragma unroll
    for (int g = 0; g < GM; ++g)
#pragma unroll
      for (int i = 0; i < 4; ++i) {
        const int row = bm + g * 64 + ty * 4 + i;
        TOut* srow = S + ((size_t)t * M_ + row) * C_;
#pragma unroll
        for (int h = 0; h < GN; ++h) {
          float sv[4];
#pragma unroll
          for (int j = 0; j < 4; ++j) {
            float y = acc[g][h][i][j] + bi[h][j];
            y = (y - mu[h][j]) * inv[h][j] * gg[h][j] + be[h][j];
            float m2 = mem[g][h][i][j] + (y - mem[g][h][i][j]) * TAU_INV;
            float s = (m2 - V_TH >= 0.0f) ? 1.0f : 0.0f;
            sv[j] = s;
            mem[g][h][i][j] = (s != 0.0f) ? 0.0f : m2;
          }
          st4(&srow[bn0 + h * 64 + tx * 4], sv);
        }
      }
  }
}

struct QKVArgs {
  const float* W[3];
  const float* bias[3];
  const float* bn[3];
  __hip_bfloat16* S[3];
};

// q,k,v fused: grid (3 * 512/128 = 12, 8192/128 = 64)
__global__ __launch_bounds__(256, 2) void qkv_kernel(
    const float* __restrict__ X, QKVArgs args)
{
  const int w  = blockIdx.x >> 2;
  const int nb = blockIdx.x & 3;
  gemm_bn_lif_body<128, 128, float, __hip_bfloat16>(
      X, args.W[w], args.bias[w], args.bn[w], args.S[w],
      blockIdx.y * 128, nb * 128);
}

// proj: grid (512/128 = 4, 8192/64 = 128)
__global__ __launch_bounds__(256, 2) void proj_kernel(
    const __hip_bfloat16* __restrict__ X, const float* __restrict__ W,
    const float* __restrict__ bias, const float* __restrict__ bn,
    float* __restrict__ S)
{
  gemm_bn_lif_body<64, 128, __hip_bfloat16, float>(
      X, W, bias, bn, S, blockIdx.y * 64, blockIdx.x * 128);
}

// ---------------------------------------------------------------------------
// Linear attention per (t,b,h): kv = k^T v / N (64x64), y = q @ kv (1024x64).
// Spikes are {0,1}: kv entries are counts/1024 and y sums <=64 multiples of
// 2^-10 -> all arithmetic here is EXACT in fp32 regardless of order.
// ---------------------------------------------------------------------------
__global__ __launch_bounds__(256) void attn_kernel(
    const __hip_bfloat16* __restrict__ Q,
    const __hip_bfloat16* __restrict__ Kk,
    const __hip_bfloat16* __restrict__ V,
    float* __restrict__ Y)
{
  __shared__ float s1[64][65];
  __shared__ float s2[64][65];
  __shared__ float kv[64][65];
  const int tid = threadIdx.x;
  const int h = blockIdx.x, b = blockIdx.y, t = blockIdx.z;
  const size_t base = ((size_t)t * B_ + b) * (size_t)N_ * C_ + (size_t)h * D_;
  const int d0 = (tid >> 4) * 4;
  const int e0 = (tid & 15) * 4;

  float acc[4][4];
#pragma unroll
  for (int i = 0; i < 4; ++i)
#pragma unroll
    for (int j = 0; j < 4; ++j) acc[i][j] = 0.0f;

  for (int nc = 0; nc < N_; nc += 64) {
#pragma unroll
    for (int i = 0; i < 16; ++i) {
      int idx = tid + i * 256;
      int r = idx >> 6, c = idx & 63;
      s1[r][c] = __bfloat162float(Kk[base + (size_t)(nc + r) * C_ + c]);
      s2[r][c] = __bfloat162float(V[base + (size_t)(nc + r) * C_ + c]);
    }
    __syncthreads();
#pragma unroll
    for (int nn = 0; nn < 64; ++nn) {
      float a[4], bb[4];
#pragma unroll
      for (int i = 0; i < 4; ++i) a[i] = s1[nn][d0 + i];
#pragma unroll
      for (int j = 0; j < 4; ++j) bb[j] = s2[nn][e0 + j];
#pragma unroll
      for (int i = 0; i < 4; ++i)
#pragma unroll
        for (int j = 0; j < 4; ++j) acc[i][j] += a[i] * bb[j];
    }
    __syncthreads();
  }
#pragma unroll
  for (int i = 0; i < 4; ++i)
#pragma unroll
    for (int j = 0; j < 4; ++j)
      kv[d0 + i][e0 + j] = acc[i][j] * (1.0f / (float)N_);
  __syncthreads();

  for (int rc = 0; rc < N_; rc += 64) {
#pragma unroll
    for (int i = 0; i < 16; ++i) {
      int idx = tid + i * 256;
      int r = idx >> 6, c = idx & 63;
      s1[r][c] = __bfloat162float(Q[base + (size_t)(rc + r) * C_ + c]);
    }
    __syncthreads();
    float o[4][4];
#pragma unroll
    for (int i = 0; i < 4; ++i)
#pragma unroll
      for (int j = 0; j < 4; ++j) o[i][j] = 0.0f;
#pragma unroll
    for (int d = 0; d < 64; ++d) {
      float a[4], bb[4];
#pragma unroll
      for (int i = 0; i < 4; ++i) a[i] = s1[d0 + i][d];
#pragma unroll
      for (int j = 0; j < 4; ++j) bb[j] = kv[d][e0 + j];
#pragma unroll
      for (int i = 0; i < 4; ++i)
#pragma unroll
        for (int j = 0; j < 4; ++j) o[i][j] += a[i] * bb[j];
    }
#pragma unroll
    for (int i = 0; i < 4; ++i)
#pragma unroll
      for (int j = 0; j < 4; ++j)
        Y[base + (size_t)(rc + d0 + i) * C_ + e0 + j] = o[i][j];
    __syncthreads();
  }
}

// ---------------------------------------------------------------------------
// Elementwise multi-step LIF (attn_lif): reads Y (T,M,C) fp32, writes bf16.
// ---------------------------------------------------------------------------
__global__ __launch_bounds__(256) void lif_ew(
    const float* __restrict__ Y, __hip_bfloat16* __restrict__ S,
    size_t npt, int T)
{
  size_t idx = (size_t)blockIdx.x * blockDim.x + threadIdx.x;
  if (idx >= npt) return;
  float mem = 0.0f;
  for (int t = 0; t < T; ++t) {
    float y = Y[(size_t)t * npt + idx];
    mem = mem + (y - mem) * TAU_INV;
    float s = (mem - V_TH >= 0.0f) ? 1.0f : 0.0f;
    S[(size_t)t * npt + idx] = __float2bfloat16(s);
    mem = (s != 0.0f) ? 0.0f : mem;
  }
}

extern "C" void kernel_launch(void* const* d_in, const int* in_sizes, int n_in,
                              void* d_out, int out_size, void* d_ws, size_t ws_size,
                              hipStream_t stream)
{
  const float* x   = (const float*)d_in[0];
  const float* Wq  = (const float*)d_in[1];
  const float* bq  = (const float*)d_in[2];
  const float* Wk  = (const float*)d_in[3];
  const float* bk  = (const float*)d_in[4];
  const float* Wv  = (const float*)d_in[5];
  const float* bv  = (const float*)d_in[6];
  const float* Wp  = (const float*)d_in[7];
  const float* bp  = (const float*)d_in[8];
  const float* bnp = (const float*)d_in[9];   // (4 layers, 4, C)
  float* out = (float*)d_out;

  char* ws = (char*)d_ws;
  const size_t nElem = (size_t)T_ * M_ * C_;   // 16,777,216
  __hip_bfloat16* q_s = (__hip_bfloat16*)ws; ws += nElem * sizeof(__hip_bfloat16);
  __hip_bfloat16* k_s = (__hip_bfloat16*)ws; ws += nElem * sizeof(__hip_bfloat16);
  __hip_bfloat16* v_s = (__hip_bfloat16*)ws; ws += nElem * sizeof(__hip_bfloat16);
  __hip_bfloat16* a_s = (__hip_bfloat16*)ws; ws += nElem * sizeof(__hip_bfloat16);
  float*          Y   = (float*)ws;          ws += nElem * sizeof(float);

  QKVArgs args;
  args.W[0] = Wq;  args.W[1] = Wk;  args.W[2] = Wv;
  args.bias[0] = bq; args.bias[1] = bk; args.bias[2] = bv;
  args.bn[0] = bnp + 0 * 4 * C_;
  args.bn[1] = bnp + 1 * 4 * C_;
  args.bn[2] = bnp + 2 * 4 * C_;
  args.S[0] = q_s; args.S[1] = k_s; args.S[2] = v_s;

  qkv_kernel<<<dim3(12, 64), dim3(16, 16), 0, stream>>>(x, args);

  attn_kernel<<<dim3(H_, B_, T_), 256, 0, stream>>>(q_s, k_s, v_s, Y);

  const size_t npt = (size_t)M_ * C_;          // 4,194,304 per timestep
  lif_ew<<<dim3((unsigned)((npt + 255) / 256)), 256, 0, stream>>>(Y, a_s, npt, T_);

  proj_kernel<<<dim3(4, 128), dim3(16, 16), 0, stream>>>(
      a_s, Wp, bp, bnp + 3 * 4 * C_, out);
}